// Round 1
// 943.512 us; speedup vs baseline: 1.0565x; 1.0565x over previous
//
#include <hip/hip_runtime.h>

#define E_NUM 8
#define DIM   1024
#define HDIM  2048
#define N_TOK 16384
#define NKA   32768
#define CAP   5120
#define REG_SZ 16777216  // elements per precast region (8*2048*1024 == 16384*1024)

typedef __bf16 bf16x8 __attribute__((ext_vector_type(8)));
typedef float  f32x4  __attribute__((ext_vector_type(4)));

__device__ __forceinline__ unsigned short f2b(float f) {
  union { float f; unsigned u; } v; v.f = f;
  unsigned r = (v.u + 0x7FFFu + ((v.u >> 16) & 1u)) >> 16;  // RNE
  return (unsigned short)r;
}

// async global->LDS, 16B per lane; LDS dest is wave-uniform base + lane*16
__device__ __forceinline__ void gload16(const void* g, void* l) {
  __builtin_amdgcn_global_load_lds(
      (const __attribute__((address_space(1))) unsigned int*)g,
      (__attribute__((address_space(3))) unsigned int*)l, 16, 0, 0);
}

template<int N> __device__ __forceinline__ void wait_vmcnt() {
  if constexpr (N == 10)      asm volatile("s_waitcnt vmcnt(10)" ::: "memory");
  else if constexpr (N == 8)  asm volatile("s_waitcnt vmcnt(8)"  ::: "memory");
  else if constexpr (N == 4)  asm volatile("s_waitcnt vmcnt(4)"  ::: "memory");
  else if constexpr (N == 2)  asm volatile("s_waitcnt vmcnt(2)"  ::: "memory");
  else if constexpr (N == 0)  asm volatile("s_waitcnt vmcnt(0)"  ::: "memory");
}

// ---------------- precast fp32 -> bf16 (W1 | Wg | W2 | X), 4 regions ---------
__global__ __launch_bounds__(256) void cast_kernel(
    const float* __restrict__ s0, const float* __restrict__ s1,
    const float* __restrict__ s2, const float* __restrict__ s3,
    unsigned short* __restrict__ dst) {
  int region = blockIdx.y;
  const float* src = region == 0 ? s0 : region == 1 ? s1 : region == 2 ? s2 : s3;
  size_t i = ((size_t)blockIdx.x * 256 + threadIdx.x) * 8;
  float4 v0 = *(const float4*)(src + i);
  float4 v1 = *(const float4*)(src + i + 4);
  ushort4 u0 = { f2b(v0.x), f2b(v0.y), f2b(v0.z), f2b(v0.w) };
  ushort4 u1 = { f2b(v1.x), f2b(v1.y), f2b(v1.z), f2b(v1.w) };
  unsigned short* o = dst + (size_t)region * REG_SZ + i;
  *(ushort4*)o = u0;
  *(ushort4*)(o + 4) = u1;
}

// ---------------- routing: one wave per token, 64 tokens per block ----------
__global__ __launch_bounds__(256) void routing_kernel(
    const float* __restrict__ x, const float* __restrict__ gate_w,
    int* __restrict__ cnt, float* __restrict__ p_sum,
    int* __restrict__ tok_of_slot, float* __restrict__ w_of_slot) {
  __shared__ float p_acc[E_NUM];
  __shared__ int   lcnt[E_NUM];
  __shared__ int   l_tok[E_NUM][128];
  __shared__ float l_w[E_NUM][128];
  __shared__ int   base[E_NUM];

  int t = threadIdx.x, lane = t & 63, wave = t >> 6;
  if (t < E_NUM) { p_acc[t] = 0.f; lcnt[t] = 0; }
  __syncthreads();

  for (int it = 0; it < 16; ++it) {
    int token = blockIdx.x * 64 + it * 4 + wave;
    const float4* xr = (const float4*)(x + (size_t)token * DIM);
    float4 xv[4];
    #pragma unroll
    for (int i = 0; i < 4; ++i) xv[i] = xr[lane + 64 * i];
    float s[E_NUM];
    #pragma unroll
    for (int e = 0; e < E_NUM; ++e) {
      const float4* gr = (const float4*)(gate_w + e * DIM);
      float acc = 0.f;
      #pragma unroll
      for (int i = 0; i < 4; ++i) {
        float4 g = gr[lane + 64 * i];
        acc += xv[i].x * g.x + xv[i].y * g.y + xv[i].z * g.z + xv[i].w * g.w;
      }
      s[e] = acc;
    }
    #pragma unroll
    for (int e = 0; e < E_NUM; ++e) {
      float v = s[e];
      #pragma unroll
      for (int off = 32; off; off >>= 1) v += __shfl_down(v, off);
      s[e] = v;
    }
    if (lane == 0) {
      float m = s[0];
      #pragma unroll
      for (int e = 1; e < E_NUM; ++e) m = fmaxf(m, s[e]);
      float p[E_NUM]; float sum = 0.f;
      #pragma unroll
      for (int e = 0; e < E_NUM; ++e) { p[e] = expf(s[e] - m); sum += p[e]; }
      float inv = 1.f / sum;
      #pragma unroll
      for (int e = 0; e < E_NUM; ++e) p[e] *= inv;
      int e0 = 0; float v0 = p[0];
      #pragma unroll
      for (int e = 1; e < E_NUM; ++e) if (p[e] > v0) { v0 = p[e]; e0 = e; }
      int e1 = -1; float v1 = -1.f;
      #pragma unroll
      for (int e = 0; e < E_NUM; ++e) if (e != e0 && p[e] > v1) { v1 = p[e]; e1 = e; }
      float denom = v0 + v1 + 1e-9f;
      float w0 = v0 / denom, w1 = v1 / denom;
      #pragma unroll
      for (int e = 0; e < E_NUM; ++e) atomicAdd(&p_acc[e], p[e]);
      int i0 = atomicAdd(&lcnt[e0], 1); l_tok[e0][i0] = token; l_w[e0][i0] = w0;
      int i1 = atomicAdd(&lcnt[e1], 1); l_tok[e1][i1] = token; l_w[e1][i1] = w1;
    }
  }
  __syncthreads();
  if (t < E_NUM) {
    base[t] = atomicAdd(&cnt[t], lcnt[t]);
    atomicAdd(&p_sum[t], p_acc[t]);
  }
  __syncthreads();
  int e = t >> 5, i0 = t & 31;
  int n = lcnt[e], b = base[e];
  for (int i = i0; i < n; i += 32) {
    int pos = b + i;
    if (pos < CAP) {
      tok_of_slot[e * CAP + pos] = l_tok[e][i];
      w_of_slot[e * CAP + pos]   = l_w[e][i];
    }
  }
}

// ---------------- loss --------------------------------------------------------
__global__ void loss_kernel(const int* __restrict__ cnt,
                            const float* __restrict__ p_sum,
                            float* __restrict__ out_loss) {
  if (threadIdx.x == 0) {
    float acc = 0.f;
    for (int e = 0; e < E_NUM; ++e)
      acc += (p_sum[e] / (float)N_TOK) * ((float)cnt[e] / (float)NKA);
    *out_loss = (float)E_NUM * acc;
  }
}

// ============== 256x256x64 8-phase GEMM template (T2+T3+T4+T5) ===============
// 512 threads = 8 waves as 2(M)x4(N); per-wave C = 128x64 = acc[8][4] f32x4.
// LDS 128 KiB: A dbuf 2x32KB at [0,32768) shorts, B dbuf at [32768,65536).
// Tile rows [256][64] bf16, 128B rows; swizzle: 16B-chunk ^= (row&7), applied as
// inverse-swizzled per-lane GLOBAL source (linear LDS dest for global_load_lds)
// and the same XOR on fragment ds_read addresses (row&7 == lane&7 on read side).

__device__ __forceinline__ void lda_f(const unsigned short* Ab, bf16x8 af[2][4],
                                      int rowbase, const int cs[2]) {
  const unsigned short* base = Ab + rowbase * 64;
  #pragma unroll
  for (int mt = 0; mt < 4; ++mt) {
    af[0][mt] = *(const bf16x8*)&base[mt * 1024 + cs[0]];
    af[1][mt] = *(const bf16x8*)&base[mt * 1024 + cs[1]];
  }
}
__device__ __forceinline__ void ldb_f(const unsigned short* Bb, bf16x8 bf[2][2],
                                      int rowbase, const int cs[2]) {
  const unsigned short* base = Bb + rowbase * 64;
  #pragma unroll
  for (int nt = 0; nt < 2; ++nt) {
    bf[0][nt] = *(const bf16x8*)&base[nt * 1024 + cs[0]];
    bf[1][nt] = *(const bf16x8*)&base[nt * 1024 + cs[1]];
  }
}

template<int MH, int NH>
__device__ __forceinline__ void mmq(f32x4 acc[8][4], const bf16x8 af[2][4],
                                    const bf16x8 bf[2][2]) {
  #pragma unroll
  for (int mt = 0; mt < 4; ++mt)
    #pragma unroll
    for (int nt = 0; nt < 2; ++nt) {
      f32x4 c = acc[MH * 4 + mt][NH * 2 + nt];
      c = __builtin_amdgcn_mfma_f32_16x16x32_bf16(af[0][mt], bf[0][nt], c, 0, 0, 0);
      c = __builtin_amdgcn_mfma_f32_16x16x32_bf16(af[1][mt], bf[1][nt], c, 0, 0, 0);
      acc[MH * 4 + mt][NH * 2 + nt] = c;
    }
}

#define A_LDS(b) (&LDS[(b) * 16384])
#define B_LDS(b) (&LDS[32768 + (b) * 16384])

// stage one 128x64 half-tile (2 x global_load_lds per wave), linear LDS dest
#define STAGE_A(b, h, kk) { \
  gload16(srcA[h][0] + (kk) * 64, &LDS[(b) * 16384 + (h) * 8192 + wave * 512]); \
  gload16(srcA[h][1] + (kk) * 64, &LDS[(b) * 16384 + (h) * 8192 + 4096 + wave * 512]); }
#define STAGE_B(b, h, kk) { \
  gload16(srcB[h][0] + (kk) * 64, &LDS[32768 + (b) * 16384 + (h) * 8192 + wave * 512]); \
  gload16(srcB[h][1] + (kk) * 64, &LDS[32768 + (b) * 16384 + (h) * 8192 + 4096 + wave * 512]); }

#define MIDBAR \
  __builtin_amdgcn_s_barrier(); \
  asm volatile("s_waitcnt lgkmcnt(0)" ::: "memory"); \
  __builtin_amdgcn_sched_barrier(0); \
  __builtin_amdgcn_s_setprio(1);

#define ENDBAR(W) \
  __builtin_amdgcn_s_setprio(0); \
  wait_vmcnt<W>(); \
  __builtin_amdgcn_s_barrier();

// one K-tile (BK=64): 4 phases over C quadrants (0,0)(0,1)(1,1)(1,0).
// staging: p1: A1(t+1)->other, p2: A0(t+2)->cur, p3: B0(t+2)->cur, p4: B1(t+2)->cur
// (every region overwritten >=1 full phase after its last read completes).
// waits: vmcnt(10) at end of p1/p2/p4 in steady state (5 half-tiles in flight).
#define TILE_BODY(W1T, W2T, W4T, S1, S2) { \
  const int cur = kt & 1, oth = cur ^ 1; \
  lda_f(A_LDS(cur), af, g64r, cs); \
  ldb_f(B_LDS(cur), bfA, q32r, cs); \
  if (S1) STAGE_A(oth, 1, kt + 1); \
  MIDBAR; mmq<0, 0>(acc, af, bfA); ENDBAR(W1T); \
  ldb_f(B_LDS(cur), bfB, 128 + q32r, cs); \
  if (S2) STAGE_A(cur, 0, kt + 2); \
  MIDBAR; mmq<0, 1>(acc, af, bfB); ENDBAR(W2T); \
  lda_f(A_LDS(cur), af, 128 + g64r, cs); \
  if (S2) STAGE_B(cur, 0, kt + 2); \
  MIDBAR; mmq<1, 1>(acc, af, bfB); ENDBAR(-1); \
  if (S2) STAGE_B(cur, 1, kt + 2); \
  MIDBAR; mmq<1, 0>(acc, af, bfA); ENDBAR(W4T); \
}

// prologue issue order matches steady state: A0(0),B0(0),B1(0),A1(0),A0(1),B0(1),B1(1)
#define GEMM_PROLOGUE { \
  STAGE_A(0, 0, 0); STAGE_B(0, 0, 0); STAGE_B(0, 1, 0); STAGE_A(0, 1, 0); \
  STAGE_A(1, 0, 1); STAGE_B(1, 0, 1); STAGE_B(1, 1, 1); \
  wait_vmcnt<10>(); \
  __builtin_amdgcn_s_barrier(); }

#define GEMM_MAIN(NTK) \
  GEMM_PROLOGUE; \
  for (int kt = 0; kt < (NTK) - 2; ++kt) TILE_BODY(10, 10, 10, true, true); \
  { int kt = (NTK) - 2; TILE_BODY(10, 8, 4, true, false); } \
  { int kt = (NTK) - 1; TILE_BODY(2, 0, -1, false, false); }

// ---------------- GEMM1: H = silu(X W1^T) * (X Wg^T), bf16 out ---------------
// B rows = interleaved [W1 row n/2 | Wg row n/2] for combined col n (N=4096);
// a 256-col tile holds matched (fc1,gate) pairs in adjacent lanes -> shfl epilogue.
__global__ __launch_bounds__(512, 2) void gemm1_kernel(
    const unsigned short* __restrict__ Wb,   // [W1|Wg|W2|X] bf16 regions
    const int* __restrict__ cnt, const int* __restrict__ tok_of_slot,
    unsigned short* __restrict__ Hbuf, int e_base) {
  int ez = blockIdx.z, e = e_base + ez;
  int cntc = min(cnt[e], CAP);
  int m0 = blockIdx.y * 256;
  if (m0 >= cntc) return;
  int n0 = blockIdx.x * 256;   // combined column base

  __shared__ __align__(16) unsigned short LDS[65536];  // 128 KiB

  int tid = threadIdx.x;
  int wave = tid >> 6, lane = tid & 63;
  int quad = lane >> 4, r = lane & 15;
  int gm = (wave >> 2) * 64, qn = (wave & 3) * 32;
  int g64r = gm + r, q32r = qn + r;
  int cs[2] = { (quad ^ (r & 7)) * 8, ((4 + quad) ^ (r & 7)) * 8 };

  const unsigned short* W1e = Wb + (size_t)e * HDIM * DIM;
  const unsigned short* Wge = Wb + REG_SZ + (size_t)e * HDIM * DIM;
  const unsigned short* Xb  = Wb + (size_t)3 * REG_SZ;

  // pre-swizzled per-lane global sources (chunk c holds global chunk c^(row&7))
  const unsigned short* srcA[2][2];
  const unsigned short* srcB[2][2];
  #pragma unroll
  for (int j = 0; j < 2; ++j) {
    int row = (j * 512 + tid) >> 3;            // row within 128-row half
    int co  = ((tid & 7) ^ (row & 7)) * 8;     // inverse-swizzled chunk
    #pragma unroll
    for (int h = 0; h < 2; ++h) {
      int slot = m0 + h * 128 + row;
      int tok = (slot < cntc) ? tok_of_slot[e * CAP + slot] : 0;
      srcA[h][j] = Xb + (size_t)tok * DIM + co;
      int nglob = n0 + h * 128 + row;
      const unsigned short* wsrc = (nglob & 1) ? Wge : W1e;
      srcB[h][j] = wsrc + (size_t)(nglob >> 1) * DIM + co;
    }
  }

  f32x4 acc[8][4];
  #pragma unroll
  for (int i = 0; i < 8; ++i)
    #pragma unroll
    for (int jj = 0; jj < 4; ++jj) acc[i][jj] = (f32x4)0.f;
  bf16x8 af[2][4], bfA[2][2], bfB[2][2];

  GEMM_MAIN(16);  // K = DIM = 16 * 64

  // epilogue: even lane holds a (fc1), odd lane holds b (gate) for same H col
  #pragma unroll
  for (int mh = 0; mh < 2; ++mh)
    #pragma unroll
    for (int mt = 0; mt < 4; ++mt)
      #pragma unroll
      for (int reg = 0; reg < 4; ++reg) {
        int row = m0 + mh * 128 + gm + mt * 16 + quad * 4 + reg;
        bool wr = (row < cntc);
        size_t basei = (size_t)(ez * CAP + row) * HDIM;
        #pragma unroll
        for (int nh = 0; nh < 2; ++nh)
          #pragma unroll
          for (int nt = 0; nt < 2; ++nt) {
            float v = acc[mh * 4 + mt][nh * 2 + nt][reg];
            float o = __shfl_xor(v, 1);
            if (wr && !(lane & 1)) {
              float a = v, b = o;
              float hval = (a / (1.f + __expf(-a))) * b;   // silu(a) * b
              int coln = n0 + nh * 128 + qn + nt * 16 + r;
              Hbuf[basei + (coln >> 1)] = f2b(hval);
            }
          }
      }
}

// ---------------- GEMM2: out += w * (H W2^T), atomic combine -----------------
__global__ __launch_bounds__(512, 2) void gemm2_kernel(
    const unsigned short* __restrict__ Hbuf, const unsigned short* __restrict__ Wb,
    const int* __restrict__ cnt, const int* __restrict__ tok_of_slot,
    const float* __restrict__ w_of_slot, float* __restrict__ out, int e_base) {
  int ez = blockIdx.z, e = e_base + ez;
  int cntc = min(cnt[e], CAP);
  int m0 = blockIdx.y * 256;
  if (m0 >= cntc) return;
  int n0 = blockIdx.x * 256;

  __shared__ __align__(16) unsigned short LDS[65536];

  int tid = threadIdx.x;
  int wave = tid >> 6, lane = tid & 63;
  int quad = lane >> 4, r = lane & 15;
  int gm = (wave >> 2) * 64, qn = (wave & 3) * 32;
  int g64r = gm + r, q32r = qn + r;
  int cs[2] = { (quad ^ (r & 7)) * 8, ((4 + quad) ^ (r & 7)) * 8 };

  const unsigned short* W2e = Wb + (size_t)2 * REG_SZ + (size_t)e * DIM * HDIM;
  const unsigned short* He  = Hbuf + (size_t)(ez * CAP) * HDIM;

  const unsigned short* srcA[2][2];
  const unsigned short* srcB[2][2];
  #pragma unroll
  for (int j = 0; j < 2; ++j) {
    int row = (j * 512 + tid) >> 3;
    int co  = ((tid & 7) ^ (row & 7)) * 8;
    #pragma unroll
    for (int h = 0; h < 2; ++h) {
      srcA[h][j] = He + (size_t)(m0 + h * 128 + row) * HDIM + co;
      srcB[h][j] = W2e + (size_t)(n0 + h * 128 + row) * HDIM + co;
    }
  }

  f32x4 acc[8][4];
  #pragma unroll
  for (int i = 0; i < 8; ++i)
    #pragma unroll
    for (int jj = 0; jj < 4; ++jj) acc[i][jj] = (f32x4)0.f;
  bf16x8 af[2][4], bfA[2][2], bfB[2][2];

  GEMM_MAIN(32);  // K = HDIM = 32 * 64

  #pragma unroll
  for (int mh = 0; mh < 2; ++mh)
    #pragma unroll
    for (int mt = 0; mt < 4; ++mt)
      #pragma unroll
      for (int reg = 0; reg < 4; ++reg) {
        int rowl = m0 + mh * 128 + gm + mt * 16 + quad * 4 + reg;
        if (rowl >= cntc) continue;
        int tok = tok_of_slot[e * CAP + rowl];
        float w = w_of_slot[e * CAP + rowl];
        float* orow = out + (size_t)tok * DIM + n0;
        #pragma unroll
        for (int nh = 0; nh < 2; ++nh)
          #pragma unroll
          for (int nt = 0; nt < 2; ++nt)
            atomicAdd(&orow[nh * 128 + qn + nt * 16 + r],
                      acc[mh * 4 + mt][nh * 2 + nt][reg] * w);
      }
}

// ---------------- launch ------------------------------------------------------
extern "C" void kernel_launch(void* const* d_in, const int* in_sizes, int n_in,
                              void* d_out, int out_size, void* d_ws, size_t ws_size,
                              hipStream_t stream) {
  const float* x        = (const float*)d_in[0];
  const float* gate_w   = (const float*)d_in[1];
  const float* fc1_w    = (const float*)d_in[2];
  const float* gating_w = (const float*)d_in[3];
  const float* fc2_w    = (const float*)d_in[4];
  float* out = (float*)d_out;

  char* ws = (char*)d_ws;
  int*   cnt         = (int*)ws;                       // 8 ints
  float* p_sum       = (float*)(ws + 128);             // 8 floats
  int*   tok_of_slot = (int*)(ws + 256);               // 40960 ints
  float* w_of_slot   = (float*)(ws + 256 + 163840);    // 40960 floats
  unsigned short* Wb   = (unsigned short*)(ws + 256 + 2 * 163840);  // 4 regions bf16 = 128 MiB
  size_t hbuf_off = 256 + 2 * 163840 + (size_t)4 * REG_SZ * 2;      // 134,545,664 B
  unsigned short* Hbuf = (unsigned short*)(ws + hbuf_off);

  // Adapt expert-chunk to available workspace (constant across calls -> graph-safe).
  const size_t per_e = (size_t)CAP * HDIM * 2;  // 20,971,520 B per expert of Hbuf
  int chunkE = 1;
  if (ws_size > hbuf_off + per_e) {
    size_t c = (ws_size - hbuf_off) / per_e;
    chunkE = c >= 8 ? 8 : (int)c;
  }

  hipMemsetAsync(ws, 0, 256, stream);                                  // cnt + p_sum
  hipMemsetAsync(d_out, 0, (size_t)out_size * sizeof(float), stream);  // atomic combine target

  cast_kernel<<<dim3(8192, 4), 256, 0, stream>>>(fc1_w, gating_w, fc2_w, x, Wb);
  routing_kernel<<<256, 256, 0, stream>>>(x, gate_w, cnt, p_sum, tok_of_slot, w_of_slot);
  loss_kernel<<<1, 64, 0, stream>>>(cnt, p_sum, out + (size_t)N_TOK * DIM);

  for (int eb = 0; eb < E_NUM; eb += chunkE) {
    int ne = (E_NUM - eb) < chunkE ? (E_NUM - eb) : chunkE;
    gemm1_kernel<<<dim3(16, 20, ne), 512, 0, stream>>>(Wb, cnt, tok_of_slot, Hbuf, eb);
    gemm2_kernel<<<dim3(4, 20, ne), 512, 0, stream>>>(Hbuf, Wb, cnt, tok_of_slot, w_of_slot, out, eb);
  }
}

// Round 4
// 924.515 us; speedup vs baseline: 1.0782x; 1.0205x over previous
//
#include <hip/hip_runtime.h>

#define E_NUM 8
#define DIM   1024
#define HDIM  2048
#define N_TOK 16384
#define NKA   32768
#define CAP   5120
#define REG_SZ 16777216  // elements per precast region (8*2048*1024 == 16384*1024)

typedef __bf16 bf16x8 __attribute__((ext_vector_type(8)));
typedef float  f32x4  __attribute__((ext_vector_type(4)));

__device__ __forceinline__ unsigned short f2b(float f) {
  union { float f; unsigned u; } v; v.f = f;
  unsigned r = (v.u + 0x7FFFu + ((v.u >> 16) & 1u)) >> 16;  // RNE
  return (unsigned short)r;
}

// Obuf aliases dead Wb regions (W1|Wg for e<6, X for e>=6); all fully consumed
// by gemm1 before gemm2 writes. cast/routing rewrite them on next graph replay.
__device__ __forceinline__ size_t obuf_off(int e) {
  return (e < 6) ? (size_t)e * ((size_t)CAP * DIM)
                 : (size_t)3 * REG_SZ + (size_t)(e - 6) * ((size_t)CAP * DIM);
}

// async global->LDS, 16B per lane; LDS dest is wave-uniform base + lane*16
__device__ __forceinline__ void gload16(const void* g, void* l) {
  __builtin_amdgcn_global_load_lds(
      (const __attribute__((address_space(1))) unsigned int*)g,
      (__attribute__((address_space(3))) unsigned int*)l, 16, 0, 0);
}

template<int N> __device__ __forceinline__ void wait_vmcnt() {
  if constexpr (N == 10)      asm volatile("s_waitcnt vmcnt(10)" ::: "memory");
  else if constexpr (N == 8)  asm volatile("s_waitcnt vmcnt(8)"  ::: "memory");
  else if constexpr (N == 4)  asm volatile("s_waitcnt vmcnt(4)"  ::: "memory");
  else if constexpr (N == 2)  asm volatile("s_waitcnt vmcnt(2)"  ::: "memory");
  else if constexpr (N == 0)  asm volatile("s_waitcnt vmcnt(0)"  ::: "memory");
}

// ---------------- precast fp32 -> bf16 (W1 | Wg | W2), 3 regions -------------
__global__ __launch_bounds__(256) void cast_kernel(
    const float* __restrict__ s0, const float* __restrict__ s1,
    const float* __restrict__ s2, const float* __restrict__ s3,
    unsigned short* __restrict__ dst) {
  int region = blockIdx.y;
  const float* src = region == 0 ? s0 : region == 1 ? s1 : region == 2 ? s2 : s3;
  size_t i = ((size_t)blockIdx.x * 256 + threadIdx.x) * 8;
  float4 v0 = *(const float4*)(src + i);
  float4 v1 = *(const float4*)(src + i + 4);
  ushort4 u0 = { f2b(v0.x), f2b(v0.y), f2b(v0.z), f2b(v0.w) };
  ushort4 u1 = { f2b(v1.x), f2b(v1.y), f2b(v1.z), f2b(v1.w) };
  unsigned short* o = dst + (size_t)region * REG_SZ + i;
  *(ushort4*)o = u0;
  *(ushort4*)(o + 4) = u1;
}

// ---------------- routing: one wave per token; also casts X -> bf16 ----------
__global__ __launch_bounds__(256) void routing_kernel(
    const float* __restrict__ x, const float* __restrict__ gate_w,
    int* __restrict__ cnt, float* __restrict__ p_sum,
    int* __restrict__ tok_of_slot, float* __restrict__ w_of_slot,
    int* __restrict__ slot_of_tok, float* __restrict__ w_of_tok,
    unsigned short* __restrict__ xb_out) {
  __shared__ float p_acc[E_NUM];
  __shared__ int   lcnt[E_NUM];
  __shared__ int   l_tok[E_NUM][128];   // packed (token<<1)|kbit
  __shared__ float l_w[E_NUM][128];
  __shared__ int   base[E_NUM];

  int t = threadIdx.x, lane = t & 63, wave = t >> 6;
  if (t < E_NUM) { p_acc[t] = 0.f; lcnt[t] = 0; }
  __syncthreads();

  for (int it = 0; it < 16; ++it) {
    int token = blockIdx.x * 64 + it * 4 + wave;
    const float4* xr = (const float4*)(x + (size_t)token * DIM);
    float4 xv[4];
    #pragma unroll
    for (int i = 0; i < 4; ++i) xv[i] = xr[lane + 64 * i];
    // fused X cast -> bf16 region (replaces cast region 3)
    unsigned short* xo = xb_out + (size_t)token * DIM;
    #pragma unroll
    for (int i = 0; i < 4; ++i) {
      ushort4 u = { f2b(xv[i].x), f2b(xv[i].y), f2b(xv[i].z), f2b(xv[i].w) };
      *(ushort4*)(xo + 4 * (lane + 64 * i)) = u;
    }
    float s[E_NUM];
    #pragma unroll
    for (int e = 0; e < E_NUM; ++e) {
      const float4* gr = (const float4*)(gate_w + e * DIM);
      float acc = 0.f;
      #pragma unroll
      for (int i = 0; i < 4; ++i) {
        float4 g = gr[lane + 64 * i];
        acc += xv[i].x * g.x + xv[i].y * g.y + xv[i].z * g.z + xv[i].w * g.w;
      }
      s[e] = acc;
    }
    #pragma unroll
    for (int e = 0; e < E_NUM; ++e) {
      float v = s[e];
      #pragma unroll
      for (int off = 32; off; off >>= 1) v += __shfl_down(v, off);
      s[e] = v;
    }
    if (lane == 0) {
      float m = s[0];
      #pragma unroll
      for (int e = 1; e < E_NUM; ++e) m = fmaxf(m, s[e]);
      float p[E_NUM]; float sum = 0.f;
      #pragma unroll
      for (int e = 0; e < E_NUM; ++e) { p[e] = expf(s[e] - m); sum += p[e]; }
      float inv = 1.f / sum;
      #pragma unroll
      for (int e = 0; e < E_NUM; ++e) p[e] *= inv;
      int e0 = 0; float v0 = p[0];
      #pragma unroll
      for (int e = 1; e < E_NUM; ++e) if (p[e] > v0) { v0 = p[e]; e0 = e; }
      int e1 = -1; float v1 = -1.f;
      #pragma unroll
      for (int e = 0; e < E_NUM; ++e) if (e != e0 && p[e] > v1) { v1 = p[e]; e1 = e; }
      float denom = v0 + v1 + 1e-9f;
      float w0 = v0 / denom, w1 = v1 / denom;
      #pragma unroll
      for (int e = 0; e < E_NUM; ++e) atomicAdd(&p_acc[e], p[e]);
      int i0 = atomicAdd(&lcnt[e0], 1); l_tok[e0][i0] = (token << 1);     l_w[e0][i0] = w0;
      int i1 = atomicAdd(&lcnt[e1], 1); l_tok[e1][i1] = (token << 1) | 1; l_w[e1][i1] = w1;
    }
  }
  __syncthreads();
  if (t < E_NUM) {
    base[t] = atomicAdd(&cnt[t], lcnt[t]);
    atomicAdd(&p_sum[t], p_acc[t]);
  }
  __syncthreads();
  int e = t >> 5, i0 = t & 31;
  int n = lcnt[e], b = base[e];
  for (int i = i0; i < n; i += 32) {
    int pos = b + i;
    if (pos < CAP) {
      int tk = l_tok[e][i];
      int token = tk >> 1, kb = tk & 1;
      int slot = e * CAP + pos;
      tok_of_slot[slot] = token;
      w_of_slot[slot]   = l_w[e][i];
      slot_of_tok[token * 2 + kb] = slot;
      w_of_tok[token * 2 + kb]    = l_w[e][i];
    }
  }
}

// ---------------- loss --------------------------------------------------------
__global__ void loss_kernel(const int* __restrict__ cnt,
                            const float* __restrict__ p_sum,
                            float* __restrict__ out_loss) {
  if (threadIdx.x == 0) {
    float acc = 0.f;
    for (int e = 0; e < E_NUM; ++e)
      acc += (p_sum[e] / (float)N_TOK) * ((float)cnt[e] / (float)NKA);
    *out_loss = (float)E_NUM * acc;
  }
}

// ============== 256x256x64 8-phase GEMM template (T2+T3+T4+T5) ===============
// 512 threads = 8 waves as 2(M)x4(N); per-wave C = 128x64 = acc[8][4] f32x4.
// LDS 128 KiB: A dbuf 2x32KB at [0,32768) shorts, B dbuf at [32768,65536).
// Tile rows [256][64] bf16; swizzle: 16B-chunk ^= (row&7), via inverse-swizzled
// per-lane GLOBAL source (linear LDS dest) + same XOR on ds_read addresses.

__device__ __forceinline__ void lda_f(const unsigned short* Ab, bf16x8 af[2][4],
                                      int rowbase, const int cs[2]) {
  const unsigned short* base = Ab + rowbase * 64;
  #pragma unroll
  for (int mt = 0; mt < 4; ++mt) {
    af[0][mt] = *(const bf16x8*)&base[mt * 1024 + cs[0]];
    af[1][mt] = *(const bf16x8*)&base[mt * 1024 + cs[1]];
  }
}
__device__ __forceinline__ void ldb_f(const unsigned short* Bb, bf16x8 bf[2][2],
                                      int rowbase, const int cs[2]) {
  const unsigned short* base = Bb + rowbase * 64;
  #pragma unroll
  for (int nt = 0; nt < 2; ++nt) {
    bf[0][nt] = *(const bf16x8*)&base[nt * 1024 + cs[0]];
    bf[1][nt] = *(const bf16x8*)&base[nt * 1024 + cs[1]];
  }
}

template<int MH, int NH>
__device__ __forceinline__ void mmq(f32x4 acc[8][4], const bf16x8 af[2][4],
                                    const bf16x8 bf[2][2]) {
  #pragma unroll
  for (int mt = 0; mt < 4; ++mt)
    #pragma unroll
    for (int nt = 0; nt < 2; ++nt) {
      f32x4 c = acc[MH * 4 + mt][NH * 2 + nt];
      c = __builtin_amdgcn_mfma_f32_16x16x32_bf16(af[0][mt], bf[0][nt], c, 0, 0, 0);
      c = __builtin_amdgcn_mfma_f32_16x16x32_bf16(af[1][mt], bf[1][nt], c, 0, 0, 0);
      acc[MH * 4 + mt][NH * 2 + nt] = c;
    }
}

#define A_LDS(b) (&LDS[(b) * 16384])
#define B_LDS(b) (&LDS[32768 + (b) * 16384])

#define STAGE_A(b, h, kk) { \
  gload16(srcA[h][0] + (kk) * 64, &LDS[(b) * 16384 + (h) * 8192 + wave * 512]); \
  gload16(srcA[h][1] + (kk) * 64, &LDS[(b) * 16384 + (h) * 8192 + 4096 + wave * 512]); }
#define STAGE_B(b, h, kk) { \
  gload16(srcB[h][0] + (kk) * 64, &LDS[32768 + (b) * 16384 + (h) * 8192 + wave * 512]); \
  gload16(srcB[h][1] + (kk) * 64, &LDS[32768 + (b) * 16384 + (h) * 8192 + 4096 + wave * 512]); }

#define MIDBAR \
  __builtin_amdgcn_s_barrier(); \
  asm volatile("s_waitcnt lgkmcnt(0)" ::: "memory"); \
  __builtin_amdgcn_sched_barrier(0); \
  __builtin_amdgcn_s_setprio(1);

#define ENDBAR(W) \
  __builtin_amdgcn_s_setprio(0); \
  wait_vmcnt<W>(); \
  __builtin_amdgcn_s_barrier();

// one K-tile (BK=64): 4 phases over C quadrants (0,0)(0,1)(1,1)(1,0).
// staging: p1: A1(t+1)->other, p2: A0(t+2)->cur, p3: B0(t+2)->cur, p4: B1(t+2)->cur
// waits: vmcnt(10) at end of p1/p2/p4 in steady state (5 half-tiles in flight).
#define TILE_BODY(W1T, W2T, W4T, S1, S2) { \
  const int cur = kt & 1, oth = cur ^ 1; \
  lda_f(A_LDS(cur), af, g64r, cs); \
  ldb_f(B_LDS(cur), bfA, q32r, cs); \
  if (S1) STAGE_A(oth, 1, kt + 1); \
  MIDBAR; mmq<0, 0>(acc, af, bfA); ENDBAR(W1T); \
  ldb_f(B_LDS(cur), bfB, 128 + q32r, cs); \
  if (S2) STAGE_A(cur, 0, kt + 2); \
  MIDBAR; mmq<0, 1>(acc, af, bfB); ENDBAR(W2T); \
  lda_f(A_LDS(cur), af, 128 + g64r, cs); \
  if (S2) STAGE_B(cur, 0, kt + 2); \
  MIDBAR; mmq<1, 1>(acc, af, bfB); ENDBAR(-1); \
  if (S2) STAGE_B(cur, 1, kt + 2); \
  MIDBAR; mmq<1, 0>(acc, af, bfA); ENDBAR(W4T); \
}

#define GEMM_PROLOGUE { \
  STAGE_A(0, 0, 0); STAGE_B(0, 0, 0); STAGE_B(0, 1, 0); STAGE_A(0, 1, 0); \
  STAGE_A(1, 0, 1); STAGE_B(1, 0, 1); STAGE_B(1, 1, 1); \
  wait_vmcnt<10>(); \
  __builtin_amdgcn_s_barrier(); }

#define GEMM_MAIN(NTK) \
  GEMM_PROLOGUE; \
  for (int kt = 0; kt < (NTK) - 2; ++kt) TILE_BODY(10, 10, 10, true, true); \
  { int kt = (NTK) - 2; TILE_BODY(10, 8, 4, true, false); } \
  { int kt = (NTK) - 1; TILE_BODY(2, 0, -1, false, false); }

// ---------------- GEMM1: H = silu(X W1^T) * (X Wg^T), bf16 out ---------------
__global__ __launch_bounds__(512, 2) void gemm1_kernel(
    const unsigned short* __restrict__ Wb,
    const int* __restrict__ cnt, const int* __restrict__ tok_of_slot,
    unsigned short* __restrict__ Hbuf, int e_base) {
  // T1: bijective XCD swizzle (one expert per XCD) + 4x4 L2 chunking
  int bx, by, bz;
  if (gridDim.z == 8) {
    int gid = blockIdx.x + (blockIdx.y << 4) + blockIdx.z * 320;  // 16*20*8 = 2560
    int xcd = gid & 7, j = gid >> 3;          // j in [0,320)
    int super = j >> 4, rem = j & 15;         // super in [0,20)
    bx = ((super & 3) << 2) + (rem & 3);
    by = ((super >> 2) << 2) + (rem >> 2);
    bz = xcd;
  } else { bx = blockIdx.x; by = blockIdx.y; bz = blockIdx.z; }

  int ez = bz, e = e_base + ez;
  int cntc = min(cnt[e], CAP);
  int m0 = by * 256;
  if (m0 >= cntc) return;
  int n0 = bx * 256;   // combined column base (interleaved W1/Wg rows)

  __shared__ __align__(16) unsigned short LDS[65536];  // 128 KiB

  int tid = threadIdx.x;
  int wave = tid >> 6, lane = tid & 63;
  int quad = lane >> 4, r = lane & 15;
  int gm = (wave >> 2) * 64, qn = (wave & 3) * 32;
  int g64r = gm + r, q32r = qn + r;
  int cs[2] = { (quad ^ (r & 7)) * 8, ((4 + quad) ^ (r & 7)) * 8 };

  const unsigned short* W1e = Wb + (size_t)e * HDIM * DIM;
  const unsigned short* Wge = Wb + REG_SZ + (size_t)e * HDIM * DIM;
  const unsigned short* Xb  = Wb + (size_t)3 * REG_SZ;

  const unsigned short* srcA[2][2];
  const unsigned short* srcB[2][2];
  #pragma unroll
  for (int j = 0; j < 2; ++j) {
    int row = (j * 512 + tid) >> 3;
    int co  = ((tid & 7) ^ (row & 7)) * 8;     // inverse-swizzled chunk
    #pragma unroll
    for (int h = 0; h < 2; ++h) {
      int slot = m0 + h * 128 + row;
      int tok = (slot < cntc) ? tok_of_slot[e * CAP + slot] : 0;
      srcA[h][j] = Xb + (size_t)tok * DIM + co;
      int nglob = n0 + h * 128 + row;
      const unsigned short* wsrc = (nglob & 1) ? Wge : W1e;
      srcB[h][j] = wsrc + (size_t)(nglob >> 1) * DIM + co;
    }
  }

  f32x4 acc[8][4];
  #pragma unroll
  for (int i = 0; i < 8; ++i)
    #pragma unroll
    for (int jj = 0; jj < 4; ++jj) acc[i][jj] = (f32x4)0.f;
  bf16x8 af[2][4], bfA[2][2], bfB[2][2];

  GEMM_MAIN(16);  // K = DIM = 16 * 64

  #pragma unroll
  for (int mh = 0; mh < 2; ++mh)
    #pragma unroll
    for (int mt = 0; mt < 4; ++mt)
      #pragma unroll
      for (int reg = 0; reg < 4; ++reg) {
        int row = m0 + mh * 128 + gm + mt * 16 + quad * 4 + reg;
        bool wr = (row < cntc);
        size_t basei = (size_t)(ez * CAP + row) * HDIM;
        #pragma unroll
        for (int nh = 0; nh < 2; ++nh)
          #pragma unroll
          for (int nt = 0; nt < 2; ++nt) {
            float v = acc[mh * 4 + mt][nh * 2 + nt][reg];
            float o = __shfl_xor(v, 1);
            if (wr && !(lane & 1)) {
              float a = v, b = o;
              float hval = (a / (1.f + __expf(-a))) * b;   // silu(a) * b
              int coln = n0 + nh * 128 + qn + nt * 16 + r;
              Hbuf[basei + (coln >> 1)] = f2b(hval);
            }
          }
      }
}

// ---------------- GEMM2: O[slot] = H W2^T (bf16), or atomic fallback ---------
__global__ __launch_bounds__(512, 2) void gemm2_kernel(
    const unsigned short* __restrict__ Hbuf, const unsigned short* __restrict__ Wb,
    const int* __restrict__ cnt, const int* __restrict__ tok_of_slot,
    const float* __restrict__ w_of_slot, float* __restrict__ out,
    unsigned short* __restrict__ obuf, int use_obuf, int e_base) {
  int bx, by, bz;
  if (gridDim.z == 8) {
    int gid = blockIdx.x + (blockIdx.y << 2) + blockIdx.z * 80;   // 4*20*8 = 640
    int xcd = gid & 7, j = gid >> 3;          // j in [0,80)
    int super = j >> 4, rem = j & 15;         // super in [0,5)
    bx = rem & 3;
    by = (super << 2) + (rem >> 2);
    bz = xcd;
  } else { bx = blockIdx.x; by = blockIdx.y; bz = blockIdx.z; }

  int ez = bz, e = e_base + ez;
  int cntc = min(cnt[e], CAP);
  int m0 = by * 256;
  if (m0 >= cntc) return;
  int n0 = bx * 256;

  __shared__ __align__(16) unsigned short LDS[65536];

  int tid = threadIdx.x;
  int wave = tid >> 6, lane = tid & 63;
  int quad = lane >> 4, r = lane & 15;
  int gm = (wave >> 2) * 64, qn = (wave & 3) * 32;
  int g64r = gm + r, q32r = qn + r;
  int cs[2] = { (quad ^ (r & 7)) * 8, ((4 + quad) ^ (r & 7)) * 8 };

  const unsigned short* W2e = Wb + (size_t)2 * REG_SZ + (size_t)e * DIM * HDIM;
  const unsigned short* He  = Hbuf + (size_t)(ez * CAP) * HDIM;

  const unsigned short* srcA[2][2];
  const unsigned short* srcB[2][2];
  #pragma unroll
  for (int j = 0; j < 2; ++j) {
    int row = (j * 512 + tid) >> 3;
    int co  = ((tid & 7) ^ (row & 7)) * 8;
    #pragma unroll
    for (int h = 0; h < 2; ++h) {
      srcA[h][j] = He + (size_t)(m0 + h * 128 + row) * HDIM + co;
      srcB[h][j] = W2e + (size_t)(n0 + h * 128 + row) * HDIM + co;
    }
  }

  f32x4 acc[8][4];
  #pragma unroll
  for (int i = 0; i < 8; ++i)
    #pragma unroll
    for (int jj = 0; jj < 4; ++jj) acc[i][jj] = (f32x4)0.f;
  bf16x8 af[2][4], bfA[2][2], bfB[2][2];

  GEMM_MAIN(32);  // K = HDIM = 32 * 64

  if (use_obuf) {
    // store raw bf16 rows per slot; combine_kernel applies routing weights
    size_t ob = obuf_off(e);
    #pragma unroll
    for (int mh = 0; mh < 2; ++mh)
      #pragma unroll
      for (int mt = 0; mt < 4; ++mt)
        #pragma unroll
        for (int reg = 0; reg < 4; ++reg) {
          int rowl = m0 + mh * 128 + gm + mt * 16 + quad * 4 + reg;
          bool wr = (rowl < cntc);
          unsigned short* orow = obuf + ob + (size_t)rowl * DIM;
          #pragma unroll
          for (int nh = 0; nh < 2; ++nh)
            #pragma unroll
            for (int nt = 0; nt < 2; ++nt) {
              float v = acc[mh * 4 + mt][nh * 2 + nt][reg];
              float o = __shfl_xor(v, 1);
              if (wr && !(lane & 1)) {
                unsigned pack = (unsigned)f2b(v) | ((unsigned)f2b(o) << 16);
                int col = n0 + nh * 128 + qn + nt * 16 + r;   // r even
                *(unsigned*)(orow + col) = pack;
              }
            }
        }
  } else {
    #pragma unroll
    for (int mh = 0; mh < 2; ++mh)
      #pragma unroll
      for (int mt = 0; mt < 4; ++mt)
        #pragma unroll
        for (int reg = 0; reg < 4; ++reg) {
          int rowl = m0 + mh * 128 + gm + mt * 16 + quad * 4 + reg;
          if (rowl >= cntc) continue;
          int tok = tok_of_slot[e * CAP + rowl];
          float w = w_of_slot[e * CAP + rowl];
          float* orow = out + (size_t)tok * DIM + n0;
          #pragma unroll
          for (int nh = 0; nh < 2; ++nh)
            #pragma unroll
            for (int nt = 0; nt < 2; ++nt)
              atomicAdd(&orow[nh * 128 + qn + nt * 16 + r],
                        acc[mh * 4 + mt][nh * 2 + nt][reg] * w);
        }
  }
}

// ---------------- combine: out[tok] = w0*O[s0] + w1*O[s1] --------------------
__global__ __launch_bounds__(256) void combine_kernel(
    const unsigned short* __restrict__ Wb,     // obuf regions live inside Wb
    const int* __restrict__ slot_of_tok, const float* __restrict__ w_of_tok,
    float* __restrict__ out) {
  int t = blockIdx.x * 256 + threadIdx.x;      // 4096 blocks -> N_TOK*64 threads
  int tok = t >> 6;
  int d0 = (t & 63) * 16;
  int s0 = slot_of_tok[2 * tok], s1 = slot_of_tok[2 * tok + 1];
  float w0 = w_of_tok[2 * tok], w1 = w_of_tok[2 * tok + 1];

  float acc[16];
  #pragma unroll
  for (int j = 0; j < 16; ++j) acc[j] = 0.f;

  if (s0 >= 0) {
    int e = s0 / CAP, pos = s0 % CAP;
    const unsigned short* rp = Wb + obuf_off(e) + (size_t)pos * DIM + d0;
    bf16x8 v0 = *(const bf16x8*)rp, v1 = *(const bf16x8*)(rp + 8);
    #pragma unroll
    for (int j = 0; j < 8; ++j) { acc[j] += w0 * (float)v0[j]; acc[8 + j] += w0 * (float)v1[j]; }
  }
  if (s1 >= 0) {
    int e = s1 / CAP, pos = s1 % CAP;
    const unsigned short* rp = Wb + obuf_off(e) + (size_t)pos * DIM + d0;
    bf16x8 v0 = *(const bf16x8*)rp, v1 = *(const bf16x8*)(rp + 8);
    #pragma unroll
    for (int j = 0; j < 8; ++j) { acc[j] += w1 * (float)v0[j]; acc[8 + j] += w1 * (float)v1[j]; }
  }
  float* o = out + (size_t)tok * DIM + d0;
  #pragma unroll
  for (int q = 0; q < 4; ++q) {
    float4 v = { acc[4 * q], acc[4 * q + 1], acc[4 * q + 2], acc[4 * q + 3] };
    *(float4*)(o + 4 * q) = v;
  }
}

// ---------------- launch ------------------------------------------------------
extern "C" void kernel_launch(void* const* d_in, const int* in_sizes, int n_in,
                              void* d_out, int out_size, void* d_ws, size_t ws_size,
                              hipStream_t stream) {
  const float* x        = (const float*)d_in[0];
  const float* gate_w   = (const float*)d_in[1];
  const float* fc1_w    = (const float*)d_in[2];
  const float* gating_w = (const float*)d_in[3];
  const float* fc2_w    = (const float*)d_in[4];
  float* out = (float*)d_out;

  char* ws = (char*)d_ws;
  int*   cnt         = (int*)ws;                                   // 8 ints
  float* p_sum       = (float*)(ws + 128);                         // 8 floats
  int*   tok_of_slot = (int*)(ws + 256);                           // 40960 ints
  float* w_of_slot   = (float*)(ws + 256 + 163840);                // 40960 floats
  int*   slot_of_tok = (int*)(ws + 256 + 2 * 163840);              // 32768 ints
  float* w_of_tok    = (float*)(ws + 256 + 2 * 163840 + 131072);   // 32768 floats
  unsigned short* Wb = (unsigned short*)(ws + 256 + 2 * 163840 + 2 * 131072);
  size_t hbuf_off = 256 + 2 * 163840 + 2 * 131072 + (size_t)4 * REG_SZ * 2;
  unsigned short* Hbuf = (unsigned short*)(ws + hbuf_off);

  const size_t per_e = (size_t)CAP * HDIM * 2;  // Hbuf bytes per expert
  int chunkE = 1;
  if (ws_size > hbuf_off + per_e) {
    size_t c = (ws_size - hbuf_off) / per_e;
    chunkE = c >= 8 ? 8 : (int)c;
  }
  int use_obuf = (chunkE == 8);

  hipMemsetAsync(ws, 0, 256, stream);                                    // cnt + p_sum
  if (use_obuf) {
    hipMemsetAsync(slot_of_tok, 0xFF, 131072, stream);                   // slots = -1
  } else {
    hipMemsetAsync(d_out, 0, (size_t)out_size * sizeof(float), stream);  // atomic target
  }

  cast_kernel<<<dim3(8192, 3), 256, 0, stream>>>(fc1_w, gating_w, fc2_w, x, Wb);
  routing_kernel<<<256, 256, 0, stream>>>(x, gate_w, cnt, p_sum, tok_of_slot,
                                          w_of_slot, slot_of_tok, w_of_tok,
                                          Wb + (size_t)3 * REG_SZ);
  loss_kernel<<<1, 64, 0, stream>>>(cnt, p_sum, out + (size_t)N_TOK * DIM);

  if (use_obuf) {
    gemm1_kernel<<<dim3(16, 20, 8), 512, 0, stream>>>(Wb, cnt, tok_of_slot, Hbuf, 0);
    gemm2_kernel<<<dim3(4, 20, 8), 512, 0, stream>>>(Hbuf, Wb, cnt, tok_of_slot,
                                                     w_of_slot, out, Wb, 1, 0);
    combine_kernel<<<4096, 256, 0, stream>>>(Wb, slot_of_tok, w_of_tok, out);
  } else {
    for (int eb = 0; eb < E_NUM; eb += chunkE) {
      int ne = (E_NUM - eb) < chunkE ? (E_NUM - eb) : chunkE;
      gemm1_kernel<<<dim3(16, 20, ne), 512, 0, stream>>>(Wb, cnt, tok_of_slot, Hbuf, eb);
      gemm2_kernel<<<dim3(4, 20, ne), 512, 0, stream>>>(Hbuf, Wb, cnt, tok_of_slot,
                                                        w_of_slot, out, Wb, 0, eb);
    }
  }
}